// Round 6
// baseline (304.964 us; speedup 1.0000x reference)
//
#include <hip/hip_runtime.h>

#define T_ 4
#define H_ 128
#define W_ 128
#define XPS 160          // padded image size (128 + 2*16)
#define WSZ 29           // search window
#define K_ 14            // neighbors kept
#define ACCS 132         // H + 2*phalf

#define SROWS 4          // pixel rows per block subtile
#define SCOLS 12         // pixel cols per block subtile
#define TR 36            // tile rows = SROWS + 32
#define TC 44            // tile cols = SCOLS + 32
#define RS 136           // tile row stride in DWORDS; 136 mod 32 == 8 -> uniform bank load
#define NBI 32           // row tiles per image (128/4)
#define NBJ 11           // col tiles per image (ceil 128/12)
#define NW 4             // waves per block
#define OPW 211          // offsets per wave (ceil 841/4)

#define HS 40            // h (row-box-sum) cols/stride
#define N2S 48           // N2 row stride in dwords (mod 32 == 16 -> 2-way = free)

// DPP row_shl:n -> lane i reads lane i+n within its 16-lane row; OOB lanes get 0.
#define DPP_SHL(x, n) __uint_as_float((unsigned)__builtin_amdgcn_update_dpp( \
        0, (int)__float_as_uint(x), 0x100 + (n), 0xF, 0xF, true))

// ---------------- kernel 1: per-(t,c) means of normalized image ----------------
__global__ void k_means(const float* __restrict__ noisy, float* __restrict__ means) {
    int tc = blockIdx.x;                       // 0..11
    const float* src = noisy + (size_t)tc * (H_ * W_);
    float s = 0.f;
    for (int i = threadIdx.x; i < H_ * W_; i += 256) s += src[i];
    __shared__ float red[256];
    red[threadIdx.x] = s;
    __syncthreads();
    for (int st = 128; st > 0; st >>= 1) {
        if ((int)threadIdx.x < st) red[threadIdx.x] += red[threadIdx.x + st];
        __syncthreads();
    }
    if (threadIdx.x == 0)
        means[tc] = red[0] * (1.f / (H_ * W_)) * (2.f / 255.f) - 1.f;
}

// ---------------- kernel 2: reflect-pad + normalize + mean-subtract ----------------
// xp layout: [t][160][160][3] channels-last
__global__ void k_pad(const float* __restrict__ noisy, const float* __restrict__ means,
                      float* __restrict__ xp) {
    int idx = blockIdx.x * 256 + threadIdx.x;
    if (idx >= T_ * XPS * XPS) return;
    int t  = idx / (XPS * XPS);
    int rr = (idx / XPS) % XPS;
    int cc = idx % XPS;
    int ry = rr - 16; if (ry < 0) ry = -ry; if (ry > H_ - 1) ry = 2 * (H_ - 1) - ry;
    int rx = cc - 16; if (rx < 0) rx = -rx; if (rx > W_ - 1) rx = 2 * (W_ - 1) - rx;
    float* dst = xp + (size_t)idx * 3;
#pragma unroll
    for (int c = 0; c < 3; c++) {
        float v = noisy[(((size_t)t * 3 + c) * H_ + ry) * W_ + rx];
        dst[c] = v * (2.f / 255.f) - 1.f - means[t * 3 + c];
    }
}

// ---------------- kernel 3: distances + top-14 + softmax + patch scatter ----------------
// 256 threads = 4 waves; block owns a 4x12 pixel subtile; waves split the 841 offsets.
// Distance via Gram decomposition: D = N2q + N2n - 2*<q,n>; inner loop = 15-fma dot
// (contiguous dwords) + DPP horizontal 5-sum. Tile stride 136 dwords -> uniform banks.
__global__ __launch_bounds__(256, 4)
void k_main(const float* __restrict__ xp, const int* __restrict__ sigma_p,
            float* __restrict__ acc) {
    __shared__ __align__(16) float tileF[TR * RS];    // 19584 B
    __shared__ unsigned kbuf[NW * K_][49];            // 10976 B (aliased: h-field, accb)
    __shared__ float N2s[32 * N2S];                   // 6144 B

    const int tid = threadIdx.x;
    const int b   = blockIdx.x;
    const int t   = b / (NBI * NBJ);
    const int rem = b % (NBI * NBJ);
    const int bi  = (rem / NBJ) * SROWS;
    const int bj  = (rem % NBJ) * SCOLS;

    // ---- stage tile: 36 rows x 33 float4 (xp rows bi..bi+35, cols bj..bj+43) ----
    const float* src = xp + ((size_t)(t * XPS + bi) * XPS + bj) * 3;
    for (int i = tid; i < TR * 33; i += 256) {
        int rr = i / 33, q = i - rr * 33;
        float4 v = *reinterpret_cast<const float4*>(src + (size_t)rr * (XPS * 3) + q * 4);
        *reinterpret_cast<float4*>(&tileF[rr * RS + q * 4]) = v;
    }
    __syncthreads();

    // ---- h pass: horizontal 5-col box sum of per-pixel squared norms ----
    // h(r,c) = sum of squares of 15 consecutive dwords at tile row r, dword c*3
    float* hbuf = reinterpret_cast<float*>(&kbuf[0][0]);   // 36*40 floats = 5760 B
    for (int i = tid; i < TR * HS; i += 256) {
        int r = i / HS, c = i - (i / HS) * HS;
        const float* tp = &tileF[r * RS + c * 3];
        float s = 0.f;
#pragma unroll
        for (int d = 0; d < 15; d++) { float v = tp[d]; s = fmaf(v, v, s); }
        hbuf[i] = s;
    }
    __syncthreads();

    // ---- N2 pass: vertical 5-row box sum -> patch norms (top-left indexed) ----
    for (int i = tid; i < 32 * HS; i += 256) {
        int r = i / HS, c = i - (i / HS) * HS;
        const float* hp = &hbuf[r * HS + c];
        N2s[r * N2S + c] = hp[0] + hp[HS] + hp[2 * HS] + hp[3 * HS] + hp[4 * HS];
    }
    __syncthreads();

    const int w    = tid >> 6;          // wave id 0..3
    const int lane = tid & 63;
    const int g    = lane >> 4;         // pixel row within subtile 0..3
    const int tj   = lane & 15;         // e-column 0..15 (pixel col if < 12)
    const bool valid = (tj < SCOLS) && (bj + tj < W_);

    // query-side patch column cached in registers: rows g..g+4 of col tj (tile +14)
    float A[5][3];
#pragma unroll
    for (int dy = 0; dy < 5; dy++)
#pragma unroll
        for (int c = 0; c < 3; c++)
            A[dy][c] = tileF[(14 + g + dy) * RS + (14 + tj) * 3 + c];
    const float N2q = N2s[(g + 14) * N2S + (tj + 14)];

    // top-14 packed keys: (f32 bits of d & ~0x3FF) | offset-index (unique, tie->lower o)
    unsigned keys[K_];
#pragma unroll
    for (int k = 0; k < K_; k++) keys[k] = 0xFFFFFF00u + k;
    unsigned kmax = 0xFFFFFF00u + (K_ - 1);

    const int o0 = w * OPW;
    const int on = (o0 + OPW <= WSZ * WSZ) ? OPW : (WSZ * WSZ - o0);
    for (int i = 0; i < on; i++) {
        int o  = o0 + i;
        int oy = o / WSZ;
        int ox = o - oy * WSZ;
        const float* bp = &tileF[(g + oy) * RS + (tj + ox) * 3];
        float cb = 0.f;
#pragma unroll
        for (int dy = 0; dy < 5; dy++) {
            cb = fmaf(A[dy][0], bp[dy * RS + 0], cb);
            cb = fmaf(A[dy][1], bp[dy * RS + 1], cb);
            cb = fmaf(A[dy][2], bp[dy * RS + 2], cb);
        }
        // horizontal 5-sum of cross terms across e-columns via DPP
        float CB = cb;
        CB += DPP_SHL(cb, 1);
        CB += DPP_SHL(cb, 2);
        CB += DPP_SHL(cb, 3);
        CB += DPP_SHL(cb, 4);
        float D = fmaf(-2.f, CB, N2q + N2s[(g + oy) * N2S + (tj + ox)]);
        D = fmaxf(D, 0.f);              // guard cancellation (self-offset) for uint keying
        unsigned key = (__float_as_uint(D) & 0xFFFFFC00u) | (unsigned)o;
        if (valid && key < kmax) {
#pragma unroll
            for (int k = 0; k < K_; k++) keys[k] = (keys[k] == kmax) ? key : keys[k];
            kmax = keys[0];
#pragma unroll
            for (int k = 1; k < K_; k++) kmax = keys[k] > kmax ? keys[k] : kmax;
        }
    }

    // ---- stash per-wave top-K (transposed: row = w*14+k, col = pixel) ----
    __syncthreads();                    // h-field reads done; kbuf reusable
    const int pxi = g * SCOLS + tj;     // 0..47 when valid
    if (valid) {
#pragma unroll
        for (int k = 0; k < K_; k++) kbuf[w * K_ + k][pxi] = keys[k];
    }
    // reset for merge
#pragma unroll
    for (int k = 0; k < K_; k++) keys[k] = 0xFFFFFF00u + k;
    kmax = 0xFFFFFF00u + (K_ - 1);
    __syncthreads();

    // ---- merge 4x14 candidates (each wave redundantly; register result) ----
    if (valid) {
        for (int j = 0; j < NW * K_; j++) {
            unsigned key = kbuf[j][pxi];
            if (key < kmax) {
#pragma unroll
                for (int k = 0; k < K_; k++) keys[k] = (keys[k] == kmax) ? key : keys[k];
                kmax = keys[0];
#pragma unroll
                for (int k = 1; k < K_; k++) kmax = keys[k] > kmax ? keys[k] : kmax;
            }
        }
    }

    // ---- softmax weights over merged 14 ----
    float sig  = (float)sigma_p[0] * (2.f / 255.f);
    float beta = 1.f / (2.f * sig * sig * 75.f);
    float wk[K_];
    int oyk[K_], oxk[K_];
    float dmin = 3.4e38f;
#pragma unroll
    for (int k = 0; k < K_; k++) {
        float dv = __uint_as_float(keys[k] & 0xFFFFFC00u);
        wk[k] = dv;
        int ok = (int)(keys[k] & 1023u);
        oyk[k] = ok / WSZ;
        oxk[k] = ok - oyk[k] * WSZ;
        dmin = fminf(dmin, dv);
    }
    float sw = 0.f;
#pragma unroll
    for (int k = 0; k < K_; k++) { float e = __expf(beta * (dmin - wk[k])); wk[k] = e; sw += e; }
    float inv = 1.f / sw;
#pragma unroll
    for (int k = 0; k < K_; k++) wk[k] *= inv;

    __syncthreads();                    // kbuf reads complete
    // ---- block-local overlap-add accumulator (overlays kbuf): 8 rows x 16 cols x 3 ----
    float* accb = reinterpret_cast<float*>(&kbuf[0][0]);
    for (int i = tid; i < 8 * 16 * 3; i += 256) accb[i] = 0.f;
    __syncthreads();

    // 25 patch positions split across the 4 waves
    for (int p = w; p < 25; p += NW) {
        int py = p / 5, px = p - py * 5;
        if (valid) {
            float s0 = 0.f, s1 = 0.f, s2 = 0.f;
#pragma unroll
            for (int k = 0; k < K_; k++) {
                const float* nb = &tileF[(g + oyk[k] + py) * RS + (tj + oxk[k] + px) * 3];
                s0 += wk[k] * nb[0];
                s1 += wk[k] * nb[1];
                s2 += wk[k] * nb[2];
            }
            float* ap = accb + ((g + py) * 16 + (tj + px)) * 3;
            atomicAdd(ap + 0, s0);
            atomicAdd(ap + 1, s1);
            atomicAdd(ap + 2, s2);
        }
    }
    __syncthreads();

    // ---- flush block accumulator to global acc ----
    for (int i = tid; i < 8 * 16 * 3; i += 256) {
        int ch = i % 3;
        int cc = (i / 3) & 15;
        int rr = i / 48;
        int gr = bi + rr, gc = bj + cc;
        if (gc < ACCS)
            atomicAdd(&acc[(((size_t)t * ACCS + gr) * ACCS + gc) * 3 + ch], accb[i]);
    }
}

// ---------------- kernel 4: normalize by overlap count, un-normalize, write out ----------------
__global__ void k_final(const float* __restrict__ acc, const float* __restrict__ means,
                        float* __restrict__ out) {
    int idx = blockIdx.x * 256 + threadIdx.x;     // [t][ch][i][j]
    if (idx >= T_ * 3 * H_ * W_) return;
    int j  = idx & 127;
    int i  = (idx >> 7) & 127;
    int ch = (idx >> 14) % 3;
    int t  = idx / (3 * H_ * W_);
    int r = i + 2, s = j + 2;
    int ny = (r < 4 ? r : 4) - (r > 127 ? r - 127 : 0) + 1;
    int nx = (s < 4 ? s : 4) - (s > 127 ? s - 127 : 0) + 1;
    float v = acc[(((size_t)t * ACCS + r) * ACCS + s) * 3 + ch] / (float)(ny * nx);
    v += means[t * 3 + ch];
    out[idx] = 127.5f * v + 127.5f;
}

extern "C" void kernel_launch(void* const* d_in, const int* in_sizes, int n_in,
                              void* d_out, int out_size, void* d_ws, size_t ws_size,
                              hipStream_t stream) {
    (void)in_sizes; (void)n_in; (void)out_size; (void)ws_size;
    const float* noisy = (const float*)d_in[0];
    const int*   sigma = (const int*)d_in[1];

    float* means = (float*)d_ws;                         // 12 floats (reserve 64)
    float* xp    = means + 64;                           // 4*160*160*3 floats
    float* acc   = xp + (size_t)T_ * XPS * XPS * 3;      // 4*132*132*3 floats
    float* out   = (float*)d_out;

    hipLaunchKernelGGL(k_means, dim3(12), dim3(256), 0, stream, noisy, means);
    hipLaunchKernelGGL(k_pad, dim3((T_ * XPS * XPS + 255) / 256), dim3(256), 0, stream,
                       noisy, means, xp);
    hipMemsetAsync(acc, 0, (size_t)T_ * ACCS * ACCS * 3 * sizeof(float), stream);
    hipLaunchKernelGGL(k_main, dim3(T_ * NBI * NBJ), dim3(256), 0, stream, xp, sigma, acc);
    hipLaunchKernelGGL(k_final, dim3((T_ * 3 * H_ * W_ + 255) / 256), dim3(256), 0, stream,
                       acc, means, out);
}

// Round 7
// 299.082 us; speedup vs baseline: 1.0197x; 1.0197x over previous
//
#include <hip/hip_runtime.h>

#define T_ 4
#define H_ 128
#define W_ 128
#define XPS 160          // padded image size (128 + 2*16)
#define WSZ 29           // search window
#define K_ 14            // neighbors kept
#define ACCS 132         // H + 2*phalf

#define SROWS 4          // pixel rows per block subtile
#define SCOLS 12         // pixel cols per block subtile
#define TR 36            // tile rows = SROWS + 32
#define RS 136           // tile row stride in DWORDS (bank-uniform for b96 reads)
#define NBI 32           // row tiles per image (128/4)
#define NBJ 11           // col tiles per image (ceil 128/12)
#define NW 4             // waves per block
#define OPW 211          // offsets per wave (ceil 841/4)

#define HS 40            // h (row-box-sum) cols/stride
#define N2S 40           // N2 row stride in dwords (mod 32 == 8 -> bank depth 2 = free)

// DPP row_shl:n -> lane i reads lane i+n within its 16-lane row; OOB lanes get 0.
#define DPP_SHL(x, n) __uint_as_float((unsigned)__builtin_amdgcn_update_dpp( \
        0, (int)__float_as_uint(x), 0x100 + (n), 0xF, 0xF, true))

// Sorted insert (keys ascending): s[i] = med3(s[i-1], s[i], key). Unconditional,
// branchless, depth-1; clang fuses min(max(..)) -> v_med3_u32.
#define SORTED_INSERT(s, key)                                        \
    do {                                                             \
        _Pragma("unroll")                                            \
        for (int _i = K_ - 1; _i >= 1; _i--)                         \
            s[_i] = min(max(key, s[_i - 1]), s[_i]);                 \
        s[0] = min(s[0], key);                                       \
    } while (0)

// ---------------- kernel 1: per-(t,c) means of normalized image ----------------
__global__ void k_means(const float* __restrict__ noisy, float* __restrict__ means) {
    int tc = blockIdx.x;                       // 0..11
    const float* src = noisy + (size_t)tc * (H_ * W_);
    float s = 0.f;
    for (int i = threadIdx.x; i < H_ * W_; i += 256) s += src[i];
    __shared__ float red[256];
    red[threadIdx.x] = s;
    __syncthreads();
    for (int st = 128; st > 0; st >>= 1) {
        if ((int)threadIdx.x < st) red[threadIdx.x] += red[threadIdx.x + st];
        __syncthreads();
    }
    if (threadIdx.x == 0)
        means[tc] = red[0] * (1.f / (H_ * W_)) * (2.f / 255.f) - 1.f;
}

// ---------------- kernel 2: reflect-pad + normalize + mean-subtract ----------------
__global__ void k_pad(const float* __restrict__ noisy, const float* __restrict__ means,
                      float* __restrict__ xp) {
    int idx = blockIdx.x * 256 + threadIdx.x;
    if (idx >= T_ * XPS * XPS) return;
    int t  = idx / (XPS * XPS);
    int rr = (idx / XPS) % XPS;
    int cc = idx % XPS;
    int ry = rr - 16; if (ry < 0) ry = -ry; if (ry > H_ - 1) ry = 2 * (H_ - 1) - ry;
    int rx = cc - 16; if (rx < 0) rx = -rx; if (rx > W_ - 1) rx = 2 * (W_ - 1) - rx;
    float* dst = xp + (size_t)idx * 3;
#pragma unroll
    for (int c = 0; c < 3; c++) {
        float v = noisy[(((size_t)t * 3 + c) * H_ + ry) * W_ + rx];
        dst[c] = v * (2.f / 255.f) - 1.f - means[t * 3 + c];
    }
}

// ---------------- kernel 3: distances + top-14 + softmax + patch scatter ----------------
__global__ __launch_bounds__(256, 4)
void k_main(const float* __restrict__ xp, const int* __restrict__ sigma_p,
            float* __restrict__ acc) {
    __shared__ __align__(16) float tileF[TR * RS];    // 19584 B
    __shared__ unsigned kbuf[NW * K_][49];            // 10976 B (aliased: h-field, accb)
    __shared__ float N2s[32 * N2S];                   // 5120 B

    const int tid = threadIdx.x;
    const int b   = blockIdx.x;
    const int t   = b / (NBI * NBJ);
    const int rem = b % (NBI * NBJ);
    const int bi  = (rem / NBJ) * SROWS;
    const int bj  = (rem % NBJ) * SCOLS;

    // ---- stage tile: 36 rows x 33 float4 ----
    const float* src = xp + ((size_t)(t * XPS + bi) * XPS + bj) * 3;
    for (int i = tid; i < TR * 33; i += 256) {
        int rr = i / 33, q = i - rr * 33;
        float4 v = *reinterpret_cast<const float4*>(src + (size_t)rr * (XPS * 3) + q * 4);
        *reinterpret_cast<float4*>(&tileF[rr * RS + q * 4]) = v;
    }
    __syncthreads();

    // ---- h pass: 15-wide squared-sum per (row, pixel-col) ----
    float* hbuf = reinterpret_cast<float*>(&kbuf[0][0]);   // 36*40 floats
    for (int i = tid; i < TR * HS; i += 256) {
        int r = i / HS, c = i - (i / HS) * HS;
        const float* tp = &tileF[r * RS + c * 3];
        float s = 0.f;
#pragma unroll
        for (int d = 0; d < 15; d++) { float v = tp[d]; s = fmaf(v, v, s); }
        hbuf[i] = s;
    }
    __syncthreads();

    // ---- N2 pass: vertical 5-row box sum -> patch norms ----
    for (int i = tid; i < 32 * HS; i += 256) {
        int r = i / HS, c = i - (i / HS) * HS;
        const float* hp = &hbuf[r * HS + c];
        N2s[r * N2S + c] = hp[0] + hp[HS] + hp[2 * HS] + hp[3 * HS] + hp[4 * HS];
    }
    __syncthreads();

    const int w    = tid >> 6;          // wave id 0..3
    const int lane = tid & 63;
    const int g    = lane >> 4;         // pixel row within subtile 0..3
    const int tj   = lane & 15;         // e-column 0..15 (pixel col if < 12)
    const bool valid = (tj < SCOLS) && (bj + tj < W_);

    // query patch column in registers
    float A[5][3];
#pragma unroll
    for (int dy = 0; dy < 5; dy++)
#pragma unroll
        for (int c = 0; c < 3; c++)
            A[dy][c] = tileF[(14 + g + dy) * RS + (14 + tj) * 3 + c];
    const float N2q = N2s[(g + 14) * N2S + (tj + 14)];

    // sorted top-14 keys (ascending): (f32 bits of D & ~0x3FF) | offset-index
    unsigned s[K_];
#pragma unroll
    for (int k = 0; k < K_; k++) s[k] = 0xFFFFFF00u + k;

    // wave w owns offset rows [oy0, oy1); rows split 8/7/7/7 (8*29=232 >= OPW covers all)
    const int oy0 = (w == 0) ? 0 : 8 + 7 * (w - 1);
    const int oy1 = (w == 0) ? 8 : 8 + 7 * w;
    for (int oy = oy0; oy < oy1; oy++) {
        const float* bp = &tileF[(g + oy) * RS + tj * 3];
        const float* np = &N2s[(g + oy) * N2S + tj];
        int o = oy * WSZ;
        for (int ox = 0; ox < WSZ; ox++, o++, bp += 3, np++) {
            float c0 = 0.f, c1 = 0.f, c2 = 0.f;
#pragma unroll
            for (int dy = 0; dy < 5; dy++) {
                c0 = fmaf(A[dy][0], bp[dy * RS + 0], c0);
                c1 = fmaf(A[dy][1], bp[dy * RS + 1], c1);
                c2 = fmaf(A[dy][2], bp[dy * RS + 2], c2);
            }
            float cb = (c0 + c1) + c2;
            // DPP tree: 5-sum over e-cols tj..tj+4
            float a2 = cb + DPP_SHL(cb, 1);
            float a4 = a2 + DPP_SHL(a2, 2);
            float CB = a4 + DPP_SHL(cb, 4);
            float D = fmaf(-2.f, CB, N2q + np[0]);
            D = fmaxf(D, 0.f);
            unsigned key = (__float_as_uint(D) & 0xFFFFFC00u) | (unsigned)o;
            SORTED_INSERT(s, key);
        }
    }

    // ---- stash per-wave top-K (transposed: row = w*14+k, col = pixel) ----
    __syncthreads();                    // h-field reads done; kbuf reusable
    const int pxi = g * SCOLS + tj;     // 0..47 when valid
    if (valid) {
#pragma unroll
        for (int k = 0; k < K_; k++) kbuf[w * K_ + k][pxi] = s[k];
    }
#pragma unroll
    for (int k = 0; k < K_; k++) s[k] = 0xFFFFFF00u + k;
    __syncthreads();

    // ---- merge 4x14 candidates ----
    if (valid) {
        for (int j = 0; j < NW * K_; j++) {
            unsigned key = kbuf[j][pxi];
            SORTED_INSERT(s, key);
        }
    }

    // ---- softmax weights over merged 14 (s sorted: dmin = s[0]) ----
    float sig  = (float)sigma_p[0] * (2.f / 255.f);
    float beta = 1.f / (2.f * sig * sig * 75.f);
    float wk[K_];
    int oyk[K_], oxk[K_];
    const float dmin = __uint_as_float(s[0] & 0xFFFFFC00u);
#pragma unroll
    for (int k = 0; k < K_; k++) {
        wk[k] = __uint_as_float(s[k] & 0xFFFFFC00u);
        int ok = (int)(s[k] & 1023u);
        oyk[k] = ok / WSZ;
        oxk[k] = ok - oyk[k] * WSZ;
    }
    float sw = 0.f;
#pragma unroll
    for (int k = 0; k < K_; k++) { float e = __expf(beta * (dmin - wk[k])); wk[k] = e; sw += e; }
    float inv = 1.f / sw;
#pragma unroll
    for (int k = 0; k < K_; k++) wk[k] *= inv;

    __syncthreads();                    // kbuf reads complete
    // ---- block-local overlap-add accumulator (overlays kbuf) ----
    float* accb = reinterpret_cast<float*>(&kbuf[0][0]);
    for (int i = tid; i < 8 * 16 * 3; i += 256) accb[i] = 0.f;
    __syncthreads();

    for (int p = w; p < 25; p += NW) {
        int py = p / 5, px = p - py * 5;
        if (valid) {
            float s0 = 0.f, s1 = 0.f, s2 = 0.f;
#pragma unroll
            for (int k = 0; k < K_; k++) {
                const float* nb = &tileF[(g + oyk[k] + py) * RS + (tj + oxk[k] + px) * 3];
                s0 += wk[k] * nb[0];
                s1 += wk[k] * nb[1];
                s2 += wk[k] * nb[2];
            }
            float* ap = accb + ((g + py) * 16 + (tj + px)) * 3;
            atomicAdd(ap + 0, s0);
            atomicAdd(ap + 1, s1);
            atomicAdd(ap + 2, s2);
        }
    }
    __syncthreads();

    // ---- flush block accumulator to global acc ----
    for (int i = tid; i < 8 * 16 * 3; i += 256) {
        int ch = i % 3;
        int cc = (i / 3) & 15;
        int rr = i / 48;
        int gr = bi + rr, gc = bj + cc;
        if (gc < ACCS)
            atomicAdd(&acc[(((size_t)t * ACCS + gr) * ACCS + gc) * 3 + ch], accb[i]);
    }
}

// ---------------- kernel 4: normalize, un-normalize, write out ----------------
__global__ void k_final(const float* __restrict__ acc, const float* __restrict__ means,
                        float* __restrict__ out) {
    int idx = blockIdx.x * 256 + threadIdx.x;     // [t][ch][i][j]
    if (idx >= T_ * 3 * H_ * W_) return;
    int j  = idx & 127;
    int i  = (idx >> 7) & 127;
    int ch = (idx >> 14) % 3;
    int t  = idx / (3 * H_ * W_);
    int r = i + 2, s = j + 2;
    int ny = (r < 4 ? r : 4) - (r > 127 ? r - 127 : 0) + 1;
    int nx = (s < 4 ? s : 4) - (s > 127 ? s - 127 : 0) + 1;
    float v = acc[(((size_t)t * ACCS + r) * ACCS + s) * 3 + ch] / (float)(ny * nx);
    v += means[t * 3 + ch];
    out[idx] = 127.5f * v + 127.5f;
}

extern "C" void kernel_launch(void* const* d_in, const int* in_sizes, int n_in,
                              void* d_out, int out_size, void* d_ws, size_t ws_size,
                              hipStream_t stream) {
    (void)in_sizes; (void)n_in; (void)out_size; (void)ws_size;
    const float* noisy = (const float*)d_in[0];
    const int*   sigma = (const int*)d_in[1];

    float* means = (float*)d_ws;                         // 12 floats (reserve 64)
    float* xp    = means + 64;                           // 4*160*160*3 floats
    float* acc   = xp + (size_t)T_ * XPS * XPS * 3;      // 4*132*132*3 floats
    float* out   = (float*)d_out;

    hipLaunchKernelGGL(k_means, dim3(12), dim3(256), 0, stream, noisy, means);
    hipLaunchKernelGGL(k_pad, dim3((T_ * XPS * XPS + 255) / 256), dim3(256), 0, stream,
                       noisy, means, xp);
    hipMemsetAsync(acc, 0, (size_t)T_ * ACCS * ACCS * 3 * sizeof(float), stream);
    hipLaunchKernelGGL(k_main, dim3(T_ * NBI * NBJ), dim3(256), 0, stream, xp, sigma, acc);
    hipLaunchKernelGGL(k_final, dim3((T_ * 3 * H_ * W_ + 255) / 256), dim3(256), 0, stream,
                       acc, means, out);
}